// Round 3
// baseline (779.799 us; speedup 1.0000x reference)
//
#include <hip/hip_runtime.h>
#include <hip/hip_bf16.h>

#define V_ 262144
#define B_ 4
#define C_ 16
#define F_ 64
#define K_ 100
#define CAP_ 8192
#define SEG_ 8   // emb row segments in k_sums

// ---- ws layout (bytes) ----
#define OFF_WEIGHTS 0
#define OFF_LABELS  4194304
#define OFF_ZERO    5242880
#define OFF_HIST    5242880
#define OFF_CNT     5275648
#define OFF_SUMS    5275712
#define OFF_CCNT    5279808
#define ZERO_BYTES  36944
#define OFF_THRESH  5279824
#define OFF_CVAL    5279840
#define OFF_CIDX    5410912

// K1: weights = prod_c proba; labels = argmax_c y (one-hot => single hot c);
// class counts; topk histogram. One float4 (4 voxels) per thread, c-loop FULLY
// unrolled so all 31 row loads are independent and the scheduler can keep them
// in flight together (MLP). y[c=0] never read: labels default 0.
// grid (V/1024, B), block 256.
__global__ __launch_bounds__(256) void k_stream(const float* __restrict__ proba,
                                                const float* __restrict__ y,
                                                float* __restrict__ weights,
                                                unsigned char* __restrict__ labels,
                                                int* __restrict__ hist,
                                                int* __restrict__ cnt)
{
    const int b = blockIdx.y;
    const int tid = threadIdx.x;
    const int q = blockIdx.x * 256 + tid;   // float4 index within batch

    __shared__ int lhist[2048];
    __shared__ int lcnt[16];
    for (int i = tid; i < 2048; i += 256) lhist[i] = 0;
    if (tid < 16) lcnt[tid] = 0;
    __syncthreads();

    const float4* pb = (const float4*)(proba + ((size_t)b * C_) * V_) + q;
    const float4* yb = (const float4*)(y     + ((size_t)b * C_) * V_) + q;
    const int s4 = V_ >> 2;                 // float4 stride between c-rows

    float4 w = pb[0];                       // c = 0 product init
    int4 l = make_int4(0, 0, 0, 0);         // label stays 0 if hot at c=0

    #pragma unroll
    for (int c = 1; c < C_; c++) {
        float4 p  = pb[c * s4];
        float4 qv = yb[c * s4];
        w.x *= p.x; w.y *= p.y; w.z *= p.z; w.w *= p.w;
        if (qv.x > 0.f) l.x = c;
        if (qv.y > 0.f) l.y = c;
        if (qv.z > 0.f) l.z = c;
        if (qv.w > 0.f) l.w = c;
    }

    ((float4*)(weights + (size_t)b * V_))[q] = w;
    ((uchar4*)(labels + (size_t)b * V_))[q] =
        make_uchar4((unsigned char)l.x, (unsigned char)l.y,
                    (unsigned char)l.z, (unsigned char)l.w);

    float wv[4] = {w.x, w.y, w.z, w.w};
    int   lv[4] = {l.x, l.y, l.z, l.w};
    #pragma unroll
    for (int j = 0; j < 4; j++) {
        atomicAdd(&lcnt[lv[j]], 1);
        atomicAdd(&lhist[__float_as_uint(wv[j]) >> 21], 1);
    }
    __syncthreads();
    if (tid < 16) atomicAdd(&cnt[tid], lcnt[tid]);
    for (int i = tid; i < 2048; i += 256)
        if (lhist[i]) atomicAdd(&hist[b * 2048 + i], lhist[i]);
}

// K2: sums[c][f] = sum_v emb[b][f][v] * [label==c]. One block per (seg, f, b):
// contiguous 128 KB stream. DEEP-MLP version: 8 float4 + 8 label dwords loaded
// per thread per outer iteration (160 B in flight per thread, 10 KB per wave)
// BEFORE any consumption — vs the VGPR=12 minimal loop that stalled every 20 B.
// Per-thread private LDS accumulators (stride 17: coprime with 32 banks, zero
// cross-thread contention).
__global__ __launch_bounds__(256) void k_sums(const float* __restrict__ emb,
                                              const unsigned char* __restrict__ labels,
                                              float* __restrict__ sums)
{
    __shared__ float acc[256 * 17];
    __shared__ float part[256];
    const int tid = threadIdx.x;
    float* my = &acc[tid * 17];
    #pragma unroll
    for (int c = 0; c < 16; c++) my[c] = 0.f;

    const int seg = blockIdx.x;             // 0..SEG_-1
    const int f   = blockIdx.y;             // 0..63
    const int b   = blockIdx.z;             // 0..3
    const int vlen = V_ / SEG_;             // 32768 voxels = 8192 float4

    const float4* src = (const float4*)(emb + (((size_t)b << 6) + f) * V_
                                        + (size_t)seg * vlen);
    const unsigned int* lb = (const unsigned int*)(labels + (size_t)b * V_
                                                   + (size_t)seg * vlen);

    // 8192 float4 / (256 threads * 8 groups) = 4 outer iterations
    for (int it = 0; it < 4; it++) {
        float4 v[8];
        unsigned lu[8];
        #pragma unroll
        for (int g = 0; g < 8; g++) {
            const int i4 = it * 2048 + g * 256 + tid;
            v[g]  = src[i4];
            lu[g] = lb[i4];
        }
        #pragma unroll
        for (int g = 0; g < 8; g++) {
            atomicAdd(&my[ lu[g]        & 0xff], v[g].x);
            atomicAdd(&my[(lu[g] >>  8) & 0xff], v[g].y);
            atomicAdd(&my[(lu[g] >> 16) & 0xff], v[g].z);
            atomicAdd(&my[ lu[g] >> 24        ], v[g].w);
        }
    }
    __syncthreads();

    // reduce 256x16 -> 16
    {
        const int c = tid & 15, r0 = (tid >> 4) << 4;
        float s = 0.f;
        #pragma unroll
        for (int i = 0; i < 16; i++) s += acc[(r0 + i) * 17 + c];
        part[tid] = s;
    }
    __syncthreads();
    if (tid < 16) {
        float s = 0.f;
        #pragma unroll
        for (int j = 0; j < 16; j++) s += part[j * 16 + tid];
        atomicAdd(&sums[(tid << 6) + f], s);
    }
}

// K3: per-batch suffix scan of 2048-bin histogram -> threshold bin T.
__global__ __launch_bounds__(256) void k_scan(const int* __restrict__ hist,
                                              int* __restrict__ thresh)
{
    const int b = blockIdx.x, tid = threadIdx.x;
    __shared__ int part[256];
    __shared__ int suf[257];
    const int* h = hist + b * 2048;
    int loc[8]; int s = 0;
    for (int i = 0; i < 8; i++) { loc[i] = h[tid * 8 + i]; s += loc[i]; }
    part[tid] = s;
    __syncthreads();
    if (tid == 0) {
        suf[256] = 0;
        for (int t = 255; t >= 0; t--) suf[t] = suf[t + 1] + part[t];
    }
    __syncthreads();
    int cg[9];
    cg[8] = suf[tid + 1];
    for (int i = 7; i >= 0; i--) cg[i] = cg[i + 1] + loc[i];
    for (int i = 0; i < 8; i++)
        if (cg[i] >= K_ && cg[i + 1] < K_) thresh[b] = tid * 8 + i;
}

// K4: collect candidates with bin >= T into per-batch buffers.
__global__ __launch_bounds__(256) void k_collect(const float* __restrict__ weights,
                                                 const int* __restrict__ thresh,
                                                 int* __restrict__ ccnt,
                                                 float* __restrict__ cval,
                                                 int* __restrict__ cidx)
{
    const int b = blockIdx.y;
    const int v = (blockIdx.x * 256 + threadIdx.x) * 4;
    const unsigned T = (unsigned)thresh[b];
    float4 w = *(const float4*)(weights + (size_t)b * V_ + v);
    float wv[4] = {w.x, w.y, w.z, w.w};
    for (int j = 0; j < 4; j++) {
        unsigned bits = __float_as_uint(wv[j]);
        if ((bits >> 21) >= T) {
            int p = atomicAdd(&ccnt[b], 1);
            if (p < CAP_) {
                cval[b * CAP_ + p] = wv[j];
                cidx[b * CAP_ + p] = v + j;
            }
        }
    }
}

// K5: exact top-K select, gather he/hec, build avg, pairwise contrastive loss.
__global__ __launch_bounds__(256) void k_final(const float* __restrict__ emb,
                                               const unsigned char* __restrict__ labels,
                                               const float* __restrict__ sums,
                                               const int* __restrict__ cnt,
                                               const int* __restrict__ ccnt,
                                               const float* __restrict__ cval,
                                               const int* __restrict__ cidx,
                                               float* __restrict__ out)
{
    const int b = blockIdx.x, tid = threadIdx.x;
    __shared__ float avg[1024];
    __shared__ float ec[K_ * 64];
    __shared__ float Ssum[K_ * 64];
    __shared__ float lsum[K_];
    __shared__ int selIdx[K_];
    __shared__ int selLab[K_];
    __shared__ int nk[16];
    __shared__ int lists[16 * K_];
    __shared__ int ofs[17];
    __shared__ float red[256];

    for (int i = tid; i < 1024; i += 256) {
        int c = i >> 6;
        float cn = (float)cnt[c];
        avg[i] = (cn > 0.f) ? 0.9f * sums[i] / fmaxf(cn, 1.f) : 0.f;
    }
    if (tid < K_) { lsum[tid] = 0.f; selIdx[tid] = 0; }
    if (tid < 16) nk[tid] = 0;

    int M = ccnt[b]; if (M > CAP_) M = CAP_;
    const float* cv = cval + b * CAP_;
    const int*   ci = cidx + b * CAP_;
    for (int i = tid; i < M; i += 256) {
        float v = cv[i]; int id = ci[i];
        int rank = 0;
        for (int j = 0; j < M; j++) {
            float vj = cv[j];
            rank += (vj > v) || (vj == v && ci[j] < id);
        }
        if (rank < K_) selIdx[rank] = id;
    }
    __syncthreads();
    for (int i = tid; i < K_; i += 256) selLab[i] = labels[(size_t)b * V_ + selIdx[i]];
    __syncthreads();
    if (tid == 0) {
        for (int i = 0; i < K_; i++) { int c = selLab[i]; lists[c * K_ + nk[c]] = i; nk[c]++; }
        int o = 0;
        for (int c = 0; c < 16; c++) { ofs[c] = o; o += nk[c] * nk[c]; }
        ofs[16] = o;
    }
    __syncthreads();

    for (int e = tid; e < K_ * 64; e += 256) {
        int k = e >> 6, f = e & 63;
        float h = emb[(((size_t)b << 6) + f) * V_ + selIdx[k]];
        int lab = selLab[k];
        float s = 0.f, ev = 0.f, lvv = 0.f;
        for (int c = 0; c < 16; c++) {
            float l = h * avg[(c << 6) + f] / 0.1f;
            float x = expf(l);
            s += x;
            if (c == lab) { ev = x; lvv = l; }
        }
        ec[e] = ev; Ssum[e] = s;
        atomicAdd(&lsum[k], lvv);
    }
    __syncthreads();

    const int P = ofs[16];
    float accv = 0.f;
    for (int p = tid; p < P; p += 256) {
        int c = 0;
        while (p >= ofs[c + 1]) c++;
        int loc = p - ofs[c];
        int n = nk[c];
        int i = lists[c * K_ + loc / n];
        int j = lists[c * K_ + loc % n];
        const float* eci = &ec[i << 6];
        const float* ecj = &ec[j << 6];
        const float* sj  = &Ssum[j << 6];
        float s = 0.f;
        for (int f = 0; f < 64; f++) s += logf(eci[f] + sj[f] - ecj[f]);
        accv += s / ((float)n * (float)n * 64.f);
    }
    for (int i2 = tid; i2 < K_; i2 += 256) {
        int c = selLab[i2];
        accv -= lsum[i2] / ((float)nk[c] * 64.f);
    }
    red[tid] = accv;
    __syncthreads();
    for (int s2 = 128; s2 > 0; s2 >>= 1) {
        if (tid < s2) red[tid] += red[tid + s2];
        __syncthreads();
    }
    if (tid == 0) atomicAdd(out, -red[0] / (float)B_);
}

extern "C" void kernel_launch(void* const* d_in, const int* in_sizes, int n_in,
                              void* d_out, int out_size, void* d_ws, size_t ws_size,
                              hipStream_t stream) {
    const float* proba = (const float*)d_in[0];
    const float* y     = (const float*)d_in[1];
    const float* emb   = (const float*)d_in[2];
    char* ws = (char*)d_ws;

    float* weights        = (float*)(ws + OFF_WEIGHTS);
    unsigned char* labels = (unsigned char*)(ws + OFF_LABELS);
    int* hist             = (int*)(ws + OFF_HIST);
    int* cnt              = (int*)(ws + OFF_CNT);
    float* sums           = (float*)(ws + OFF_SUMS);
    int* ccnt             = (int*)(ws + OFF_CCNT);
    int* thresh           = (int*)(ws + OFF_THRESH);
    float* cval           = (float*)(ws + OFF_CVAL);
    int* cidx             = (int*)(ws + OFF_CIDX);
    float* out            = (float*)d_out;

    hipMemsetAsync(ws + OFF_ZERO, 0, ZERO_BYTES, stream);
    hipMemsetAsync(out, 0, sizeof(float), stream);

    k_stream<<<dim3(V_ / 1024, B_), 256, 0, stream>>>(proba, y, weights, labels, hist, cnt);
    k_sums<<<dim3(SEG_, F_, B_), 256, 0, stream>>>(emb, labels, sums);
    k_scan<<<B_, 256, 0, stream>>>(hist, thresh);
    k_collect<<<dim3(V_ / 1024, B_), 256, 0, stream>>>(weights, thresh, ccnt, cval, cidx);
    k_final<<<B_, 256, 0, stream>>>(emb, labels, sums, cnt, ccnt, cval, cidx, out);
}

// Round 4
// 535.200 us; speedup vs baseline: 1.4570x; 1.4570x over previous
//
#include <hip/hip_runtime.h>
#include <hip/hip_bf16.h>

#define V_ 262144
#define B_ 4
#define C_ 16
#define F_ 64
#define K_ 100
#define CAP_ 8192
#define SEG_ 8   // emb row segments in k_sums

// ---- ws layout (bytes) ----
#define OFF_WEIGHTS 0
#define OFF_LABELS  4194304
#define OFF_ZERO    5242880
#define OFF_HIST    5242880
#define OFF_CNT     5275648
#define OFF_SUMS    5275712
#define OFF_CCNT    5279808
#define ZERO_BYTES  36944
#define OFF_THRESH  5279824
#define OFF_CVAL    5279840
#define OFF_CIDX    5410912

// K1 (UNCHANGED this round — control): weights = prod_c proba; labels = argmax_c y;
// class counts; topk histogram. grid (V/1024, B), block 256.
__global__ __launch_bounds__(256) void k_stream(const float* __restrict__ proba,
                                                const float* __restrict__ y,
                                                float* __restrict__ weights,
                                                unsigned char* __restrict__ labels,
                                                int* __restrict__ hist,
                                                int* __restrict__ cnt)
{
    const int b = blockIdx.y;
    const int tid = threadIdx.x;
    const int q = blockIdx.x * 256 + tid;   // float4 index within batch

    __shared__ int lhist[2048];
    __shared__ int lcnt[16];
    for (int i = tid; i < 2048; i += 256) lhist[i] = 0;
    if (tid < 16) lcnt[tid] = 0;
    __syncthreads();

    const float4* pb = (const float4*)(proba + ((size_t)b * C_) * V_) + q;
    const float4* yb = (const float4*)(y     + ((size_t)b * C_) * V_) + q;
    const int s4 = V_ >> 2;                 // float4 stride between c-rows

    float4 w = pb[0];                       // c = 0 product init
    int4 l = make_int4(0, 0, 0, 0);         // label stays 0 if hot at c=0

    #pragma unroll
    for (int c = 1; c < C_; c++) {
        float4 p  = pb[c * s4];
        float4 qv = yb[c * s4];
        w.x *= p.x; w.y *= p.y; w.z *= p.z; w.w *= p.w;
        if (qv.x > 0.f) l.x = c;
        if (qv.y > 0.f) l.y = c;
        if (qv.z > 0.f) l.z = c;
        if (qv.w > 0.f) l.w = c;
    }

    ((float4*)(weights + (size_t)b * V_))[q] = w;
    ((uchar4*)(labels + (size_t)b * V_))[q] =
        make_uchar4((unsigned char)l.x, (unsigned char)l.y,
                    (unsigned char)l.z, (unsigned char)l.w);

    float wv[4] = {w.x, w.y, w.z, w.w};
    int   lv[4] = {l.x, l.y, l.z, l.w};
    #pragma unroll
    for (int j = 0; j < 4; j++) {
        atomicAdd(&lcnt[lv[j]], 1);
        atomicAdd(&lhist[__float_as_uint(wv[j]) >> 21], 1);
    }
    __syncthreads();
    if (tid < 16) atomicAdd(&cnt[tid], lcnt[tid]);
    for (int i = tid; i < 2048; i += 256)
        if (lhist[i]) atomicAdd(&hist[b * 2048 + i], lhist[i]);
}

// K2: sums[c][f] = sum_v emb[b][f][v] * [label==c]. One block per (seg, f, b),
// contiguous 128 KB stream. ATOMIC-FREE version: the hot loop accumulates into
// 16 per-thread VGPRs via fully-unrolled compare-select-add (all indices
// compile-time constant — no scratch, no LDS traffic, no ds_add serialization).
// Diagnostic for the 345-us plateau shared by all three prior versions, whose
// only invariant was 1 divergent-address LDS atomic per element.
__global__ __launch_bounds__(256) void k_sums(const float* __restrict__ emb,
                                              const unsigned char* __restrict__ labels,
                                              float* __restrict__ sums)
{
    __shared__ float lacc[256 * 17];
    __shared__ float part[256];
    const int tid = threadIdx.x;

    const int seg = blockIdx.x;             // 0..SEG_-1
    const int f   = blockIdx.y;             // 0..63
    const int b   = blockIdx.z;             // 0..3
    const int vlen = V_ / SEG_;             // 32768 voxels = 8192 float4

    const float4* src = (const float4*)(emb + (((size_t)b << 6) + f) * V_
                                        + (size_t)seg * vlen);
    const unsigned int* lb = (const unsigned int*)(labels + (size_t)b * V_
                                                   + (size_t)seg * vlen);

    float acc[16];
    #pragma unroll
    for (int c = 0; c < 16; c++) acc[c] = 0.f;

    // 8192 float4 / (256 threads * 8 groups) = 4 outer iterations
    for (int it = 0; it < 4; it++) {
        float4 v[8];
        unsigned lu[8];
        #pragma unroll
        for (int g = 0; g < 8; g++) {
            const int i4 = it * 2048 + g * 256 + tid;
            v[g]  = src[i4];
            lu[g] = lb[i4];
        }
        __builtin_amdgcn_sched_barrier(0);   // keep the 16 loads clustered (MLP)
        #pragma unroll
        for (int g = 0; g < 8; g++) {
            const int l0 =  lu[g]        & 0xff;
            const int l1 = (lu[g] >>  8) & 0xff;
            const int l2 = (lu[g] >> 16) & 0xff;
            const int l3 =  lu[g] >> 24;
            #pragma unroll
            for (int c = 0; c < 16; c++) {
                float s = (l0 == c ? v[g].x : 0.f);
                s      += (l1 == c ? v[g].y : 0.f);
                s      += (l2 == c ? v[g].z : 0.f);
                s      += (l3 == c ? v[g].w : 0.f);
                acc[c] += s;
            }
        }
    }

    // one-time spill to private LDS slots (plain stores, stride 17 = conflict-free)
    #pragma unroll
    for (int c = 0; c < 16; c++) lacc[tid * 17 + c] = acc[c];
    __syncthreads();

    // reduce 256x16 -> 16
    {
        const int c = tid & 15, r0 = (tid >> 4) << 4;
        float s = 0.f;
        #pragma unroll
        for (int i = 0; i < 16; i++) s += lacc[(r0 + i) * 17 + c];
        part[tid] = s;
    }
    __syncthreads();
    if (tid < 16) {
        float s = 0.f;
        #pragma unroll
        for (int j = 0; j < 16; j++) s += part[j * 16 + tid];
        atomicAdd(&sums[(tid << 6) + f], s);
    }
}

// K3: per-batch suffix scan of 2048-bin histogram -> threshold bin T.
__global__ __launch_bounds__(256) void k_scan(const int* __restrict__ hist,
                                              int* __restrict__ thresh)
{
    const int b = blockIdx.x, tid = threadIdx.x;
    __shared__ int part[256];
    __shared__ int suf[257];
    const int* h = hist + b * 2048;
    int loc[8]; int s = 0;
    for (int i = 0; i < 8; i++) { loc[i] = h[tid * 8 + i]; s += loc[i]; }
    part[tid] = s;
    __syncthreads();
    if (tid == 0) {
        suf[256] = 0;
        for (int t = 255; t >= 0; t--) suf[t] = suf[t + 1] + part[t];
    }
    __syncthreads();
    int cg[9];
    cg[8] = suf[tid + 1];
    for (int i = 7; i >= 0; i--) cg[i] = cg[i + 1] + loc[i];
    for (int i = 0; i < 8; i++)
        if (cg[i] >= K_ && cg[i + 1] < K_) thresh[b] = tid * 8 + i;
}

// K4: collect candidates with bin >= T into per-batch buffers.
__global__ __launch_bounds__(256) void k_collect(const float* __restrict__ weights,
                                                 const int* __restrict__ thresh,
                                                 int* __restrict__ ccnt,
                                                 float* __restrict__ cval,
                                                 int* __restrict__ cidx)
{
    const int b = blockIdx.y;
    const int v = (blockIdx.x * 256 + threadIdx.x) * 4;
    const unsigned T = (unsigned)thresh[b];
    float4 w = *(const float4*)(weights + (size_t)b * V_ + v);
    float wv[4] = {w.x, w.y, w.z, w.w};
    for (int j = 0; j < 4; j++) {
        unsigned bits = __float_as_uint(wv[j]);
        if ((bits >> 21) >= T) {
            int p = atomicAdd(&ccnt[b], 1);
            if (p < CAP_) {
                cval[b * CAP_ + p] = wv[j];
                cidx[b * CAP_ + p] = v + j;
            }
        }
    }
}

// K5: exact top-K select, gather he/hec, build avg, pairwise contrastive loss.
__global__ __launch_bounds__(256) void k_final(const float* __restrict__ emb,
                                               const unsigned char* __restrict__ labels,
                                               const float* __restrict__ sums,
                                               const int* __restrict__ cnt,
                                               const int* __restrict__ ccnt,
                                               const float* __restrict__ cval,
                                               const int* __restrict__ cidx,
                                               float* __restrict__ out)
{
    const int b = blockIdx.x, tid = threadIdx.x;
    __shared__ float avg[1024];
    __shared__ float ec[K_ * 64];
    __shared__ float Ssum[K_ * 64];
    __shared__ float lsum[K_];
    __shared__ int selIdx[K_];
    __shared__ int selLab[K_];
    __shared__ int nk[16];
    __shared__ int lists[16 * K_];
    __shared__ int ofs[17];
    __shared__ float red[256];

    for (int i = tid; i < 1024; i += 256) {
        int c = i >> 6;
        float cn = (float)cnt[c];
        avg[i] = (cn > 0.f) ? 0.9f * sums[i] / fmaxf(cn, 1.f) : 0.f;
    }
    if (tid < K_) { lsum[tid] = 0.f; selIdx[tid] = 0; }
    if (tid < 16) nk[tid] = 0;

    int M = ccnt[b]; if (M > CAP_) M = CAP_;
    const float* cv = cval + b * CAP_;
    const int*   ci = cidx + b * CAP_;
    for (int i = tid; i < M; i += 256) {
        float v = cv[i]; int id = ci[i];
        int rank = 0;
        for (int j = 0; j < M; j++) {
            float vj = cv[j];
            rank += (vj > v) || (vj == v && ci[j] < id);
        }
        if (rank < K_) selIdx[rank] = id;
    }
    __syncthreads();
    for (int i = tid; i < K_; i += 256) selLab[i] = labels[(size_t)b * V_ + selIdx[i]];
    __syncthreads();
    if (tid == 0) {
        for (int i = 0; i < K_; i++) { int c = selLab[i]; lists[c * K_ + nk[c]] = i; nk[c]++; }
        int o = 0;
        for (int c = 0; c < 16; c++) { ofs[c] = o; o += nk[c] * nk[c]; }
        ofs[16] = o;
    }
    __syncthreads();

    for (int e = tid; e < K_ * 64; e += 256) {
        int k = e >> 6, f = e & 63;
        float h = emb[(((size_t)b << 6) + f) * V_ + selIdx[k]];
        int lab = selLab[k];
        float s = 0.f, ev = 0.f, lvv = 0.f;
        for (int c = 0; c < 16; c++) {
            float l = h * avg[(c << 6) + f] / 0.1f;
            float x = expf(l);
            s += x;
            if (c == lab) { ev = x; lvv = l; }
        }
        ec[e] = ev; Ssum[e] = s;
        atomicAdd(&lsum[k], lvv);
    }
    __syncthreads();

    const int P = ofs[16];
    float accv = 0.f;
    for (int p = tid; p < P; p += 256) {
        int c = 0;
        while (p >= ofs[c + 1]) c++;
        int loc = p - ofs[c];
        int n = nk[c];
        int i = lists[c * K_ + loc / n];
        int j = lists[c * K_ + loc % n];
        const float* eci = &ec[i << 6];
        const float* ecj = &ec[j << 6];
        const float* sj  = &Ssum[j << 6];
        float s = 0.f;
        for (int f = 0; f < 64; f++) s += logf(eci[f] + sj[f] - ecj[f]);
        accv += s / ((float)n * (float)n * 64.f);
    }
    for (int i2 = tid; i2 < K_; i2 += 256) {
        int c = selLab[i2];
        accv -= lsum[i2] / ((float)nk[c] * 64.f);
    }
    red[tid] = accv;
    __syncthreads();
    for (int s2 = 128; s2 > 0; s2 >>= 1) {
        if (tid < s2) red[tid] += red[tid + s2];
        __syncthreads();
    }
    if (tid == 0) atomicAdd(out, -red[0] / (float)B_);
}

extern "C" void kernel_launch(void* const* d_in, const int* in_sizes, int n_in,
                              void* d_out, int out_size, void* d_ws, size_t ws_size,
                              hipStream_t stream) {
    const float* proba = (const float*)d_in[0];
    const float* y     = (const float*)d_in[1];
    const float* emb   = (const float*)d_in[2];
    char* ws = (char*)d_ws;

    float* weights        = (float*)(ws + OFF_WEIGHTS);
    unsigned char* labels = (unsigned char*)(ws + OFF_LABELS);
    int* hist             = (int*)(ws + OFF_HIST);
    int* cnt              = (int*)(ws + OFF_CNT);
    float* sums           = (float*)(ws + OFF_SUMS);
    int* ccnt             = (int*)(ws + OFF_CCNT);
    int* thresh           = (int*)(ws + OFF_THRESH);
    float* cval           = (float*)(ws + OFF_CVAL);
    int* cidx             = (int*)(ws + OFF_CIDX);
    float* out            = (float*)d_out;

    hipMemsetAsync(ws + OFF_ZERO, 0, ZERO_BYTES, stream);
    hipMemsetAsync(out, 0, sizeof(float), stream);

    k_stream<<<dim3(V_ / 1024, B_), 256, 0, stream>>>(proba, y, weights, labels, hist, cnt);
    k_sums<<<dim3(SEG_, F_, B_), 256, 0, stream>>>(emb, labels, sums);
    k_scan<<<B_, 256, 0, stream>>>(hist, thresh);
    k_collect<<<dim3(V_ / 1024, B_), 256, 0, stream>>>(weights, thresh, ccnt, cval, cidx);
    k_final<<<B_, 256, 0, stream>>>(emb, labels, sums, cnt, ccnt, cval, cidx, out);
}